// Round 1
// baseline (1061.070 us; speedup 1.0000x reference)
//
#include <hip/hip_runtime.h>
#include <math.h>

#define BB  128
#define NN  1024
#define KNN 40
#define HH  64

// ---------------------------------------------------------------------------
// Kernel A: per query point (row), find 40-NN and compute the sigmoid weight.
// One wave per row; 4 waves (256 threads) per block; 16 rows per block.
// Grid = BB * (NN/16) = 8192 blocks.
//
// Selection: per-lane 16 distances -> Batcher sort in registers (static
// indices only) -> sorted lists spilled to per-wave LDS -> 40 extractions via
// wave-min; each extraction immediately updates the 64 hidden-unit max-pool
// (lane l owns hidden unit l; max_j relu(s_j+b) == relu(max_j s_j + b)).
// ---------------------------------------------------------------------------
__global__ __launch_bounds__(256, 4) void knn_weight_kernel(
    const float* __restrict__ pts,  // [B,3,N]
    const float* __restrict__ W1,   // [3,H]
    const float* __restrict__ b1,   // [H]
    const float* __restrict__ W2,   // [H]
    const float* __restrict__ b2,   // [1]
    float* __restrict__ wout)       // [B,N]
{
    __shared__ float4 sp[NN];                    // 16 KB: (x,y,z,0)
    __shared__ float  listD[4][16 * 64];         // 16 KB: per-wave sorted dists
    __shared__ unsigned short listI[4][16 * 64]; //  8 KB: per-wave indices

    const int b    = blockIdx.x >> 6;
    const int grp  = blockIdx.x & 63;
    const int tid  = threadIdx.x;
    const int w    = tid >> 6;
    const int lane = tid & 63;

    const float* px = pts + b * 3 * NN;
    for (int i = tid; i < NN; i += 256)
        sp[i] = make_float4(px[i], px[NN + i], px[2 * NN + i], 0.0f);
    __syncthreads();

    const float w1x = W1[lane];           // W1[0][lane]
    const float w1y = W1[HH + lane];      // W1[1][lane]
    const float w1z = W1[2 * HH + lane];  // W1[2][lane]
    const float b1v = b1[lane];
    const float w2v = W2[lane];
    const float b2v = b2[0];

    float* myD          = listD[w];
    unsigned short* myI = listI[w];

    for (int r = 0; r < 4; ++r) {
        const int n = grp * 16 + w * 4 + r;
        const float4 q = sp[n];

        // --- distances: 16 per lane, static registers ---
        float d[16];
        int   ix[16];
        #pragma unroll
        for (int t = 0; t < 16; ++t) {
            const int m = t * 64 + lane;
            const float4 p = sp[m];
            const float dx = p.x - q.x, dy = p.y - q.y, dz = p.z - q.z;
            d[t]  = fmaf(dx, dx, fmaf(dy, dy, dz * dz));
            ix[t] = m;
        }

        // --- Batcher odd-even merge sort, ascending; all indices constant ---
        #pragma unroll
        for (int p = 1; p < 16; p <<= 1) {
            #pragma unroll
            for (int k = p; k >= 1; k >>= 1) {
                #pragma unroll
                for (int j = (k & (p - 1)); j + k < 16; j += 2 * k) {
                    #pragma unroll
                    for (int i = 0; i < k; ++i) {
                        const int a = i + j, c = i + j + k;
                        if (c < 16 && (a / (2 * p)) == (c / (2 * p))) {
                            const bool  sw  = d[c] < d[a];
                            const float tda = sw ? d[c] : d[a];
                            const float tdc = sw ? d[a] : d[c];
                            const int   tia = sw ? ix[c] : ix[a];
                            const int   tic = sw ? ix[a] : ix[c];
                            d[a] = tda; d[c] = tdc; ix[a] = tia; ix[c] = tic;
                        }
                    }
                }
            }
        }

        // --- spill ranks 1..15 to LDS rows 0..14; row 15 = +inf sentinel ---
        #pragma unroll
        for (int t = 1; t < 16; ++t) {
            myD[(t - 1) * 64 + lane] = d[t];
            myI[(t - 1) * 64 + lane] = (unsigned short)ix[t];
        }
        myD[15 * 64 + lane] = __builtin_inff();
        myI[15 * 64 + lane] = 0;

        // --- 40 extractions, fused with MLP max-pool update ---
        float curD = d[0];
        int   curI = ix[0];
        int   ptr  = 0;
        float pool = -__builtin_inff();

        for (int it = 0; it < KNN; ++it) {
            float mval = curD;
            #pragma unroll
            for (int s = 1; s < 64; s <<= 1)
                mval = fminf(mval, __shfl_xor(mval, s));
            const unsigned long long bal = __ballot(curD == mval);
            const int wl   = (int)__ffsll(bal) - 1;
            const int widx = __shfl(curI, wl);
            const float4 c = sp[widx];                       // uniform broadcast
            const float s1 = fmaf(c.x, w1x, fmaf(c.y, w1y, c.z * w1z));
            pool = fmaxf(pool, s1);
            if (lane == wl) {                                // winner advances
                curD = myD[ptr * 64 + lane];
                curI = (int)myI[ptr * 64 + lane];
                ++ptr;
            }
        }

        // --- sigmoid(pooled @ W2 + b2) ---
        const float pooled = fmaxf(pool + b1v, 0.0f);
        float acc = pooled * w2v;
        #pragma unroll
        for (int s = 1; s < 64; s <<= 1)
            acc += __shfl_xor(acc, s);
        if (lane == 0)
            wout[b * NN + n] = 1.0f / (1.0f + expf(-(acc + b2v)));
    }
}

// ---------------------------------------------------------------------------
// Kernel B: weighted order-2 jet fit per batch. One block (256 thr) per batch.
// ---------------------------------------------------------------------------
__global__ __launch_bounds__(256) void fit_kernel(
    const float* __restrict__ pts,   // [B,3,N]
    const float* __restrict__ wbuf,  // [B,N]
    float* __restrict__ out)         // [B,3]
{
    const int b    = blockIdx.x;
    const int tid  = threadIdx.x;
    const int lane = tid & 63;
    const int wv   = tid >> 6;
    const float* x    = pts + b * 3 * NN;
    const float* y    = x + NN;
    const float* z    = y + NN;
    const float* wrow = wbuf + b * NN;

    __shared__ float red[4][3];
    __shared__ float red27[4][27];
    __shared__ float sh_h;
    __shared__ int   sh_useW;

    // pass 1: mean|x|, mean|y|, valid_count
    float sax = 0.f, say = 0.f, cnt = 0.f;
    for (int i = tid; i < NN; i += 256) {
        sax += fabsf(x[i]);
        say += fabsf(y[i]);
        if (wrow[i] > 0.001f) cnt += 1.0f;
    }
    #pragma unroll
    for (int s = 1; s < 64; s <<= 1) {
        sax += __shfl_xor(sax, s);
        say += __shfl_xor(say, s);
        cnt += __shfl_xor(cnt, s);
    }
    if (lane == 0) { red[wv][0] = sax; red[wv][1] = say; red[wv][2] = cnt; }
    __syncthreads();
    if (tid == 0) {
        float SX = 0.f, SY = 0.f, C = 0.f;
        for (int q2 = 0; q2 < 4; ++q2) { SX += red[q2][0]; SY += red[q2][1]; C += red[q2][2]; }
        float h = (SX / (float)NN + SY / (float)NN) * 0.5f;
        if (fabsf(h) < 1e-4f) h = 0.1f;
        sh_h    = h;
        sh_useW = (C > 18.5f) ? 1 : 0;   // valid_count > 18
    }
    __syncthreads();
    const float h    = sh_h;
    const int   useW = sh_useW;
    const float ih   = 1.0f / h;

    // pass 2: XtX (21 unique) + XtY (6)
    float S[27];
    #pragma unroll
    for (int i = 0; i < 27; ++i) S[i] = 0.f;

    for (int i = tid; i < NN; i += 256) {
        const float wt = useW ? wrow[i] : 1.0f;
        const float xs = x[i] * ih;
        const float ys = y[i] * ih;
        const float zz = z[i];
        const float A[6] = { xs, ys, xs * xs, ys * ys, xs * ys, 1.0f };
        int c = 0;
        #pragma unroll
        for (int p = 0; p < 6; ++p) {
            const float wp = wt * A[p];
            #pragma unroll
            for (int q2 = p; q2 < 6; ++q2) {
                S[c] = fmaf(wp, A[q2], S[c]);
                ++c;
            }
            S[21 + p] = fmaf(wp, zz, S[21 + p]);
        }
    }
    #pragma unroll
    for (int i = 0; i < 27; ++i) {
        float v = S[i];
        #pragma unroll
        for (int s = 1; s < 64; s <<= 1) v += __shfl_xor(v, s);
        if (lane == 0) red27[wv][i] = v;
    }
    __syncthreads();

    if (tid == 0) {
        double T[27];
        for (int i = 0; i < 27; ++i)
            T[i] = (double)red27[0][i] + (double)red27[1][i]
                 + (double)red27[2][i] + (double)red27[3][i];

        double M[6][7];
        int c = 0;
        for (int p = 0; p < 6; ++p)
            for (int q2 = p; q2 < 6; ++q2) {
                M[p][q2] = T[c]; M[q2][p] = T[c]; ++c;
            }
        for (int p = 0; p < 6; ++p) M[p][6] = T[21 + p];

        // Gaussian elimination with partial pivoting (fp64, single thread)
        for (int col = 0; col < 6; ++col) {
            int piv = col; double best = fabs(M[col][col]);
            for (int rr = col + 1; rr < 6; ++rr) {
                const double a = fabs(M[rr][col]);
                if (a > best) { best = a; piv = rr; }
            }
            if (piv != col)
                for (int cc = col; cc < 7; ++cc) {
                    const double t = M[col][cc]; M[col][cc] = M[piv][cc]; M[piv][cc] = t;
                }
            const double f = 1.0 / M[col][col];
            for (int rr = col + 1; rr < 6; ++rr) {
                const double m = M[rr][col] * f;
                for (int cc = col; cc < 7; ++cc) M[rr][cc] -= m * M[col][cc];
            }
        }
        double beta[6];
        for (int rr = 5; rr >= 0; --rr) {
            double s = M[rr][6];
            for (int cc = rr + 1; cc < 6; ++cc) s -= M[rr][cc] * beta[cc];
            beta[rr] = s / M[rr][rr];
        }
        const double hd  = (double)h;
        const double nx  = -(beta[0] / hd);
        const double ny  = -(beta[1] / hd);
        const double nrm = sqrt(nx * nx + ny * ny + 1.0);
        out[b * 3 + 0] = (float)(nx / nrm);
        out[b * 3 + 1] = (float)(ny / nrm);
        out[b * 3 + 2] = (float)(1.0 / nrm);
    }
}

extern "C" void kernel_launch(void* const* d_in, const int* in_sizes, int n_in,
                              void* d_out, int out_size, void* d_ws, size_t ws_size,
                              hipStream_t stream) {
    const float* pts = (const float*)d_in[0];
    const float* W1  = (const float*)d_in[1];
    const float* b1  = (const float*)d_in[2];
    const float* W2  = (const float*)d_in[3];
    const float* b2  = (const float*)d_in[4];
    // d_in[5] = k (==40), compile-time constant here.
    float* wbuf = (float*)d_ws;   // [B*N] f32 = 512 KB scratch
    float* out  = (float*)d_out;  // [B,3] f32

    knn_weight_kernel<<<BB * (NN / 16), 256, 0, stream>>>(pts, W1, b1, W2, b2, wbuf);
    fit_kernel<<<BB, 256, 0, stream>>>(pts, wbuf, out);
}

// Round 2
// 287.019 us; speedup vs baseline: 3.6969x; 3.6969x over previous
//
#include <hip/hip_runtime.h>
#include <math.h>

#define BB  128
#define NN  1024
#define KNN 40
#define HH  64

// ---------------------------------------------------------------------------
// Kernel A: per query point (row), find the 40-NN set via ballot-popcount
// bisection on float-as-uint distance keys, then fused MLP max-pool + sigmoid.
// One wave per row-group of 4; 4 waves (256 threads) per block; 16 rows/block.
// Grid = BB * (NN/16) = 8192 blocks. LDS 20 KB -> 8 blocks/CU.
//
// Selection: cnt(pivot) = #{d < pivot} computed with 16 v_cmp + scalar
// s_bcnt1 per evaluation (no shuffle reductions, wave-uniform result).
// Bisection exits when cnt == 40 (select d < pivot == exact 40 smallest);
// tie fallback closes the interval and selects d_bits < hi (dup-inclusive,
// same semantics as top_k boundary with duplicates).
// ---------------------------------------------------------------------------
__global__ __launch_bounds__(256, 8) void knn_weight_kernel(
    const float* __restrict__ pts,  // [B,3,N]
    const float* __restrict__ W1,   // [3,H]
    const float* __restrict__ b1,   // [H]
    const float* __restrict__ W2,   // [H]
    const float* __restrict__ b2,   // [1]
    float* __restrict__ wout)       // [B,N]
{
    __shared__ float4 sp[NN];        // 16 KB: (x,y,z,0)
    __shared__ float4 cbuf[4][64];   //  4 KB: per-wave compacted neighbors

    const int b    = blockIdx.x >> 6;
    const int grp  = blockIdx.x & 63;
    const int tid  = threadIdx.x;
    const int w    = tid >> 6;
    const int lane = tid & 63;

    const float* px = pts + b * 3 * NN;
    for (int i = tid; i < NN; i += 256)
        sp[i] = make_float4(px[i], px[NN + i], px[2 * NN + i], 0.0f);
    __syncthreads();

    const float w1x = W1[lane];           // W1[0][lane]
    const float w1y = W1[HH + lane];      // W1[1][lane]
    const float w1z = W1[2 * HH + lane];  // W1[2][lane]
    const float b1v = b1[lane];
    const float w2v = W2[lane];
    const float b2v = b2[0];

    for (int r = 0; r < 4; ++r) {
        const int n = grp * 16 + w * 4 + r;
        const float4 q = sp[n];

        // --- 16 distances per lane, as monotone uint keys ---
        unsigned key[16];
        #pragma unroll
        for (int t = 0; t < 16; ++t) {
            const float4 p = sp[t * 64 + lane];
            const float dx = p.x - q.x, dy = p.y - q.y, dz = p.z - q.z;
            const float d  = fmaf(dx, dx, fmaf(dy, dy, dz * dz));
            key[t] = __float_as_uint(d);   // d >= 0 -> uint order == float order
        }

        // --- bisection for the 40-NN threshold ---
        unsigned lo = 0u, hi = 0x7f800000u;  // (cnt(lo)=0) < 40 <= (cnt(inf)=1024)
        unsigned thr = 0u;
        int found = 0;
        while (hi - lo > 1u) {
            const unsigned mid = (lo + hi) >> 1;
            int c = 0;
            #pragma unroll
            for (int t = 0; t < 16; ++t)
                c += (int)__popcll(__ballot(key[t] < mid));
            if (c == KNN) { thr = mid; found = 1; break; }
            if (c < KNN) lo = mid; else hi = mid;
        }
        if (!found) thr = hi;   // boundary ties: dup-inclusive

        // --- ballot-scan compaction of passing points into cbuf[w] ---
        int base = 0;
        #pragma unroll
        for (int t = 0; t < 16; ++t) {
            const bool p = key[t] < thr;
            const unsigned long long bal = __ballot(p);
            const unsigned below = __builtin_amdgcn_mbcnt_hi(
                (unsigned)(bal >> 32),
                __builtin_amdgcn_mbcnt_lo((unsigned)(bal & 0xffffffffu), 0u));
            if (p) {
                const int pos = base + (int)below;
                if (pos < 64) cbuf[w][pos] = sp[t * 64 + lane];
            }
            base += (int)__popcll(bal);
        }
        const int m = base < 64 ? base : 64;

        // --- fused MLP max-pool: lane = hidden unit, broadcast LDS reads ---
        float pool = -__builtin_inff();
        for (int j = 0; j < m; ++j) {
            const float4 c = cbuf[w][j];
            const float s1 = fmaf(c.x, w1x, fmaf(c.y, w1y, c.z * w1z));
            pool = fmaxf(pool, s1);
        }

        // --- sigmoid(relu(pool + b1) @ W2 + b2) ---
        const float pooled = fmaxf(pool + b1v, 0.0f);
        float acc = pooled * w2v;
        #pragma unroll
        for (int s = 1; s < 64; s <<= 1)
            acc += __shfl_xor(acc, s);
        if (lane == 0)
            wout[b * NN + n] = 1.0f / (1.0f + expf(-(acc + b2v)));
    }
}

// ---------------------------------------------------------------------------
// Kernel B: weighted order-2 jet fit per batch. One block (256 thr) per batch.
// ---------------------------------------------------------------------------
__global__ __launch_bounds__(256) void fit_kernel(
    const float* __restrict__ pts,   // [B,3,N]
    const float* __restrict__ wbuf,  // [B,N]
    float* __restrict__ out)         // [B,3]
{
    const int b    = blockIdx.x;
    const int tid  = threadIdx.x;
    const int lane = tid & 63;
    const int wv   = tid >> 6;
    const float* x    = pts + b * 3 * NN;
    const float* y    = x + NN;
    const float* z    = y + NN;
    const float* wrow = wbuf + b * NN;

    __shared__ float red[4][3];
    __shared__ float red27[4][27];
    __shared__ float sh_h;
    __shared__ int   sh_useW;

    // pass 1: mean|x|, mean|y|, valid_count
    float sax = 0.f, say = 0.f, cnt = 0.f;
    for (int i = tid; i < NN; i += 256) {
        sax += fabsf(x[i]);
        say += fabsf(y[i]);
        if (wrow[i] > 0.001f) cnt += 1.0f;
    }
    #pragma unroll
    for (int s = 1; s < 64; s <<= 1) {
        sax += __shfl_xor(sax, s);
        say += __shfl_xor(say, s);
        cnt += __shfl_xor(cnt, s);
    }
    if (lane == 0) { red[wv][0] = sax; red[wv][1] = say; red[wv][2] = cnt; }
    __syncthreads();
    if (tid == 0) {
        float SX = 0.f, SY = 0.f, C = 0.f;
        for (int q2 = 0; q2 < 4; ++q2) { SX += red[q2][0]; SY += red[q2][1]; C += red[q2][2]; }
        float h = (SX / (float)NN + SY / (float)NN) * 0.5f;
        if (fabsf(h) < 1e-4f) h = 0.1f;
        sh_h    = h;
        sh_useW = (C > 18.5f) ? 1 : 0;   // valid_count > 18
    }
    __syncthreads();
    const float h    = sh_h;
    const int   useW = sh_useW;
    const float ih   = 1.0f / h;

    // pass 2: XtX (21 unique) + XtY (6)
    float S[27];
    #pragma unroll
    for (int i = 0; i < 27; ++i) S[i] = 0.f;

    for (int i = tid; i < NN; i += 256) {
        const float wt = useW ? wrow[i] : 1.0f;
        const float xs = x[i] * ih;
        const float ys = y[i] * ih;
        const float zz = z[i];
        const float A[6] = { xs, ys, xs * xs, ys * ys, xs * ys, 1.0f };
        int c = 0;
        #pragma unroll
        for (int p = 0; p < 6; ++p) {
            const float wp = wt * A[p];
            #pragma unroll
            for (int q2 = p; q2 < 6; ++q2) {
                S[c] = fmaf(wp, A[q2], S[c]);
                ++c;
            }
            S[21 + p] = fmaf(wp, zz, S[21 + p]);
        }
    }
    #pragma unroll
    for (int i = 0; i < 27; ++i) {
        float v = S[i];
        #pragma unroll
        for (int s = 1; s < 64; s <<= 1) v += __shfl_xor(v, s);
        if (lane == 0) red27[wv][i] = v;
    }
    __syncthreads();

    if (tid == 0) {
        double T[27];
        for (int i = 0; i < 27; ++i)
            T[i] = (double)red27[0][i] + (double)red27[1][i]
                 + (double)red27[2][i] + (double)red27[3][i];

        double M[6][7];
        int c = 0;
        for (int p = 0; p < 6; ++p)
            for (int q2 = p; q2 < 6; ++q2) {
                M[p][q2] = T[c]; M[q2][p] = T[c]; ++c;
            }
        for (int p = 0; p < 6; ++p) M[p][6] = T[21 + p];

        // Gaussian elimination with partial pivoting (fp64, single thread)
        for (int col = 0; col < 6; ++col) {
            int piv = col; double best = fabs(M[col][col]);
            for (int rr = col + 1; rr < 6; ++rr) {
                const double a = fabs(M[rr][col]);
                if (a > best) { best = a; piv = rr; }
            }
            if (piv != col)
                for (int cc = col; cc < 7; ++cc) {
                    const double t = M[col][cc]; M[col][cc] = M[piv][cc]; M[piv][cc] = t;
                }
            const double f = 1.0 / M[col][col];
            for (int rr = col + 1; rr < 6; ++rr) {
                const double m = M[rr][col] * f;
                for (int cc = col; cc < 7; ++cc) M[rr][cc] -= m * M[col][cc];
            }
        }
        double beta[6];
        for (int rr = 5; rr >= 0; --rr) {
            double s = M[rr][6];
            for (int cc = rr + 1; cc < 6; ++cc) s -= M[rr][cc] * beta[cc];
            beta[rr] = s / M[rr][rr];
        }
        const double hd  = (double)h;
        const double nx  = -(beta[0] / hd);
        const double ny  = -(beta[1] / hd);
        const double nrm = sqrt(nx * nx + ny * ny + 1.0);
        out[b * 3 + 0] = (float)(nx / nrm);
        out[b * 3 + 1] = (float)(ny / nrm);
        out[b * 3 + 2] = (float)(1.0 / nrm);
    }
}

extern "C" void kernel_launch(void* const* d_in, const int* in_sizes, int n_in,
                              void* d_out, int out_size, void* d_ws, size_t ws_size,
                              hipStream_t stream) {
    const float* pts = (const float*)d_in[0];
    const float* W1  = (const float*)d_in[1];
    const float* b1  = (const float*)d_in[2];
    const float* W2  = (const float*)d_in[3];
    const float* b2  = (const float*)d_in[4];
    // d_in[5] = k (==40), compile-time constant here.
    float* wbuf = (float*)d_ws;   // [B*N] f32 = 512 KB scratch
    float* out  = (float*)d_out;  // [B,3] f32

    knn_weight_kernel<<<BB * (NN / 16), 256, 0, stream>>>(pts, W1, b1, W2, b2, wbuf);
    fit_kernel<<<BB, 256, 0, stream>>>(pts, wbuf, out);
}